// Round 3
// baseline (205.971 us; speedup 1.0000x reference)
//
#include <hip/hip_runtime.h>
#include <cstring>
#include <cstdint>
#include <cmath>

// ---------------------------------------------------------------------------
// Threefry-2x32 (20 rounds) — exact JAX PRNG
// ---------------------------------------------------------------------------
__host__ __device__ static inline uint32_t rotl32(uint32_t v, int r) {
    return __builtin_rotateleft32(v, (unsigned)r);
}

__host__ __device__ static inline void tf2x32(uint32_t k0, uint32_t k1,
                                              uint32_t& x0, uint32_t& x1) {
    uint32_t ks2 = k0 ^ k1 ^ 0x1BD11BDAu;
    x0 += k0; x1 += k1;
#define TFR(r) { x0 += x1; x1 = rotl32(x1, r); x1 ^= x0; }
    TFR(13) TFR(15) TFR(26) TFR(6)
    x0 += k1;  x1 += ks2 + 1u;
    TFR(17) TFR(29) TFR(16) TFR(24)
    x0 += ks2; x1 += k0 + 2u;
    TFR(13) TFR(15) TFR(26) TFR(6)
    x0 += k0;  x1 += k1 + 3u;
    TFR(17) TFR(29) TFR(16) TFR(24)
    x0 += k1;  x1 += ks2 + 4u;
    TFR(13) TFR(15) TFR(26) TFR(6)
    x0 += ks2; x1 += k0 + 5u;
#undef TFR
}

// Partitionable-mode 32-bit random bits for flat index i: counter (0,i); out0^out1
__host__ __device__ static inline uint32_t pbits(uint32_t k0, uint32_t k1, uint32_t i) {
    uint32_t a = 0u, b = i;
    tf2x32(k0, k1, a, b);
    return a ^ b;
}

// bits -> uniform [0,1) exactly as jax
__host__ __device__ static inline float bits_to_u01(uint32_t bits) {
    uint32_t u = (bits >> 9) | 0x3f800000u;
    float f; memcpy(&f, &u, 4);
    return f - 1.0f;
}

// XLA ErfInv (Giles 2010, float32) — PRECISE version (host-side params only)
__host__ static inline float erfinv_f(float x) {
    float w = -log1pf(-x * x);
    float p;
    if (w < 5.0f) {
        w = w - 2.5f;
        p = 2.81022636e-08f;
        p = fmaf(p, w, 3.43273939e-07f);
        p = fmaf(p, w, -3.5233877e-06f);
        p = fmaf(p, w, -4.39150654e-06f);
        p = fmaf(p, w, 0.00021858087f);
        p = fmaf(p, w, -0.00125372503f);
        p = fmaf(p, w, -0.00417768164f);
        p = fmaf(p, w, 0.246640727f);
        p = fmaf(p, w, 1.50140941f);
    } else {
        w = sqrtf(w) - 3.0f;
        p = -0.000200214257f;
        p = fmaf(p, w, 0.000100950558f);
        p = fmaf(p, w, 0.00134934322f);
        p = fmaf(p, w, -0.00367342844f);
        p = fmaf(p, w, 0.00573950773f);
        p = fmaf(p, w, -0.0076224613f);
        p = fmaf(p, w, 0.00943887047f);
        p = fmaf(p, w, 1.00167406f);
        p = fmaf(p, w, 2.83297682f);
    }
    return p * x;
}

__host__ static inline float normal_from_bits(uint32_t bits) {
    const float LO = -0.999999940395355224609375f;  // -1 + 2^-24
    float u01 = bits_to_u01(bits);
    float u = u01 * 2.0f + LO;
    u = (u > LO) ? u : LO;
    return 1.4142135623730951f * erfinv_f(u);
}

// ---------------------------------------------------------------------------
// Device-fast normal: same bit semantics; log1p(-x^2) via fma + v_log_f32.
// fmaf(x,-x,1) is single-rounded (no cancellation); __log2f ~1ulp -> noise
// error ~1e-6, far under threshold. Polynomial identical to XLA's.
// ---------------------------------------------------------------------------
__device__ __forceinline__ float normal_fast(uint32_t bits) {
    const float LO = -0.999999940395355224609375f;
    uint32_t u = (bits >> 9) | 0x3f800000u;
    float x = fmaf(__uint_as_float(u) - 1.0f, 2.0f, LO);
    x = fmaxf(x, LO);
    float t = fmaf(x, -x, 1.0f);            // 1 - x^2, single rounding
    float lg = __log2f(t);                   // v_log_f32
    float p;
    if (__builtin_expect(lg > -7.2134752044448170f, 1)) {   // w < 5
        float w = fmaf(lg, -0.6931471805599453f, -2.5f);    // -ln2*lg - 2.5
        p = 2.81022636e-08f;
        p = fmaf(p, w, 3.43273939e-07f);
        p = fmaf(p, w, -3.5233877e-06f);
        p = fmaf(p, w, -4.39150654e-06f);
        p = fmaf(p, w, 0.00021858087f);
        p = fmaf(p, w, -0.00125372503f);
        p = fmaf(p, w, -0.00417768164f);
        p = fmaf(p, w, 0.246640727f);
        p = fmaf(p, w, 1.50140941f);
    } else {
        float w = sqrtf(lg * -0.6931471805599453f) - 3.0f;
        p = -0.000200214257f;
        p = fmaf(p, w, 0.000100950558f);
        p = fmaf(p, w, 0.00134934322f);
        p = fmaf(p, w, -0.00367342844f);
        p = fmaf(p, w, 0.00573950773f);
        p = fmaf(p, w, -0.0076224613f);
        p = fmaf(p, w, 0.00943887047f);
        p = fmaf(p, w, 1.00167406f);
        p = fmaf(p, w, 2.83297682f);
    }
    return 1.4142135623730951f * p * x;
}

// ---------------------------------------------------------------------------
// Host-side float32 4x4 matrix helpers (unchanged — exact reference mirror)
// ---------------------------------------------------------------------------
struct M4 { float m[4][4]; };

static M4 m4_eye() {
    M4 r;
    for (int i = 0; i < 4; ++i)
        for (int j = 0; j < 4; ++j) r.m[i][j] = (i == j) ? 1.0f : 0.0f;
    return r;
}
static M4 m4_mul(const M4& A, const M4& B) {
    M4 r;
    for (int i = 0; i < 4; ++i)
        for (int j = 0; j < 4; ++j) {
            float s = 0.0f;
            for (int k = 0; k < 4; ++k) s += A.m[i][k] * B.m[k][j];
            r.m[i][j] = s;
        }
    return r;
}
static M4 m4_scale(float sx, float sy, float sz) {
    M4 r = m4_eye(); r.m[0][0] = sx; r.m[1][1] = sy; r.m[2][2] = sz; return r;
}
static M4 m4_trans(float tx, float ty, float tz) {
    M4 r = m4_eye(); r.m[0][3] = tx; r.m[1][3] = ty; r.m[2][3] = tz; return r;
}
static M4 m4_rotz(float th) {
    float c = cosf(th), s = sinf(th);
    M4 r = m4_eye();
    r.m[0][0] = c; r.m[0][1] = -s; r.m[1][0] = s; r.m[1][1] = c;
    return r;
}
static M4 m4_rotluma(float th) {
    const float a  = 0.57735026918962576f;
    const float a2 = 1.0f / 3.0f;
    float c = cosf(th), s = sinf(th), cc = 1.0f - c;
    float d  = a2 * cc + c;
    float mm = a2 * cc - a * s;
    float pp = a2 * cc + a * s;
    M4 r = m4_eye();
    r.m[0][0] = d;  r.m[0][1] = mm; r.m[0][2] = pp;
    r.m[1][0] = pp; r.m[1][1] = d;  r.m[1][2] = mm;
    r.m[2][0] = mm; r.m[2][1] = pp; r.m[2][2] = d;
    return r;
}

// ---------------------------------------------------------------------------
struct AugParams {
    float G[16][12];
    float C[16][12];
    float sigma[16];
    float cx[16], cy[16], cz[16];
    uint32_t nk0, nk1;
};

static void build_params(AugParams& P) {
    uint32_t sk0[24], sk1[24];
    for (int j = 0; j < 24; ++j) {
        uint32_t a = 0u, b = (uint32_t)j;
        tf2x32(0u, 42u, a, b);
        sk0[j] = a; sk1[j] = b;
    }

    float u_xf[16], u_r90[16], u_ti[48], n_sc[16], u_r1[16], n_an[16], u_r2[16];
    float n_tf[48], n_br[16], n_ct[16], u_lf[16], u_hue[16], n_sat[16], n_sig[16], u_cut[48];

    auto fill_u = [&](int j, int n, float* o) {
        for (int i = 0; i < n; ++i) o[i] = bits_to_u01(pbits(sk0[j], sk1[j], (uint32_t)i));
    };
    auto fill_n = [&](int j, int n, float* o) {
        for (int i = 0; i < n; ++i) o[i] = normal_from_bits(pbits(sk0[j], sk1[j], (uint32_t)i));
    };

    fill_u(0, 16, u_xf);  fill_u(1, 16, u_r90);  fill_u(2, 48, u_ti);
    fill_n(3, 16, n_sc);  fill_u(4, 16, u_r1);   fill_n(5, 16, n_an);
    fill_u(6, 16, u_r2);  fill_n(7, 48, n_tf);   fill_n(8, 16, n_br);
    fill_n(9, 16, n_ct);  fill_u(10, 16, u_lf);  fill_u(11, 16, u_hue);
    fill_n(12, 16, n_sat); fill_n(13, 16, n_sig); fill_u(15, 48, u_cut);
    P.nk0 = sk0[14]; P.nk1 = sk1[14];

    const float PI_F = 3.14159265358979323846f;
    const float HPI_F = 1.5707963267948966f;

    for (int b = 0; b < 16; ++b) {
        M4 G = m4_eye();
        float i1 = floorf(u_xf[b] * 2.0f);
        G = m4_mul(G, m4_scale(1.0f - 2.0f * i1, 1.0f, 1.0f));
        float i2 = floorf(u_r90[b] * 4.0f);
        G = m4_mul(G, m4_rotz(-HPI_F * i2));
        float t0 = (u_ti[3 * b + 0] * 2.0f - 1.0f) * 0.125f;
        float t1 = (u_ti[3 * b + 1] * 2.0f - 1.0f) * 0.125f;
        float t2 = (u_ti[3 * b + 2] * 2.0f - 1.0f) * 0.125f;
        G = m4_mul(G, m4_trans(-rintf(t0 * 64.0f), -rintf(t1 * 64.0f), -rintf(t2 * 64.0f)));
        float s = exp2f(n_sc[b] * 0.2f);
        G = m4_mul(G, m4_scale(1.0f / s, 1.0f / s, 1.0f / s));
        float th1 = (u_r1[b] * 2.0f - 1.0f) * PI_F;
        G = m4_mul(G, m4_rotz(-th1));
        float s2 = exp2f(n_an[b] * 0.2f);
        G = m4_mul(G, m4_scale(1.0f / s2, s2, 1.0f));
        float th2 = (u_r2[b] * 2.0f - 1.0f) * PI_F;
        G = m4_mul(G, m4_rotz(-th2));
        float f0 = n_tf[3 * b + 0] * 0.125f;
        float f1 = n_tf[3 * b + 1] * 0.125f;
        float f2 = n_tf[3 * b + 2] * 0.125f;
        G = m4_mul(G, m4_trans(-f0 * 64.0f, -f1 * 64.0f, -f2 * 64.0f));

        M4 C = m4_eye();
        float br = n_br[b] * 0.2f;
        C = m4_mul(m4_trans(br, br, br), C);
        float ct = exp2f(n_ct[b] * 0.5f);
        C = m4_mul(m4_scale(ct, ct, ct), C);
        const float va = 0.57735026918962576f;
        float v4[4] = { va, va, va, 0.0f };
        float ilf = floorf(u_lf[b] * 2.0f);
        M4 L;
        for (int r = 0; r < 4; ++r)
            for (int c = 0; c < 4; ++c)
                L.m[r][c] = ((r == c) ? 1.0f : 0.0f) - 2.0f * (v4[r] * v4[c]) * ilf;
        C = m4_mul(L, C);
        float thh = (u_hue[b] * 2.0f - 1.0f) * PI_F;
        C = m4_mul(m4_rotluma(thh), C);
        float ss = exp2f(n_sat[b] * 1.0f);
        M4 S;
        for (int r = 0; r < 4; ++r)
            for (int c = 0; c < 4; ++c) {
                float vv = v4[r] * v4[c];
                S.m[r][c] = vv + (((r == c) ? 1.0f : 0.0f) - vv) * ss;
            }
        C = m4_mul(S, C);

        P.sigma[b] = fabsf(n_sig[b]) * 0.1f;
        P.cx[b] = u_cut[3 * b + 0];
        P.cy[b] = u_cut[3 * b + 1];
        P.cz[b] = u_cut[3 * b + 2];
        for (int r = 0; r < 3; ++r)
            for (int c = 0; c < 4; ++c) {
                P.G[b][r * 4 + c] = G.m[r][c];
                P.C[b][r * 4 + c] = C.m[r][c];
            }
    }
}

// ---------------------------------------------------------------------------
// Fused augment kernel: 4 x-consecutive voxels per thread, all 3 channels.
// Gather first (loads in flight), then RNG+color+cutout, float4 stores.
// ---------------------------------------------------------------------------
__global__ __launch_bounds__(256, 4) void aug_kernel(const float* __restrict__ in,
                                                     float* __restrict__ out,
                                                     AugParams P) {
    const int tid = blockIdx.x * 256 + threadIdx.x;   // 0 .. 1048575
    const int b  = tid >> 16;                          // 65536 threads / batch
    const int vq = tid & 65535;
    const int x4 = (vq & 15) << 2;                     // x = x4..x4+3
    const int y  = (vq >> 4) & 63;
    const int z  = vq >> 10;

    const float G0 = P.G[b][0], G1 = P.G[b][1], G2 = P.G[b][2],  G3  = P.G[b][3];
    const float G4 = P.G[b][4], G5 = P.G[b][5], G6 = P.G[b][6],  G7  = P.G[b][7];
    const float G8 = P.G[b][8], G9 = P.G[b][9], G10 = P.G[b][10], G11 = P.G[b][11];

    const float hx0 = (float)x4 - 31.5f;
    const float hy  = (float)y  - 31.5f;
    const float hz  = (float)z  - 31.5f;

    const float sxb = G0 * hx0 + G1 * hy + G2  * hz + G3  + 31.5f;
    const float syb = G4 * hx0 + G5 * hy + G6  * hz + G7  + 31.5f;
    const float szb = G8 * hx0 + G9 * hy + G10 * hz + G11 + 31.5f;

    const float* __restrict__ imb = in + (size_t)b * 786432;

    float vr[4], vg[4], vb[4];

#pragma unroll
    for (int i = 0; i < 4; ++i) {
        float sx = fmaf((float)i, G0, sxb);
        float sy = fmaf((float)i, G4, syb);
        float sz = fmaf((float)i, G8, szb);

        float fx = floorf(sx), fy = floorf(sy), fz = floorf(sz);
        float wx = sx - fx, wy = sy - fy, wz = sz - fz;
        int ix = (int)fx, iy = (int)fy, iz = (int)fz;

        // validity folded into weights (invalid axis-corner -> 0 weight)
        float xw0 = ((unsigned)ix       < 64u) ? 1.0f - wx : 0.0f;
        float xw1 = ((unsigned)(ix + 1) < 64u) ? wx        : 0.0f;
        float yw0 = ((unsigned)iy       < 64u) ? 1.0f - wy : 0.0f;
        float yw1 = ((unsigned)(iy + 1) < 64u) ? wy        : 0.0f;
        float zw0 = ((unsigned)iz       < 64u) ? 1.0f - wz : 0.0f;
        float zw1 = ((unsigned)(iz + 1) < 64u) ? wz        : 0.0f;

        // clamped offsets (memory safety; garbage*0 is fine, input finite)
        int xc0 = min(max(ix, 0), 63),           xc1 = min(max(ix + 1, 0), 63);
        int yo0 = min(max(iy, 0), 63) << 6,      yo1 = min(max(iy + 1, 0), 63) << 6;
        int zo0 = min(max(iz, 0), 63) << 12,     zo1 = min(max(iz + 1, 0), 63) << 12;

        float w00 = zw0 * yw0, w01 = zw0 * yw1, w10 = zw1 * yw0, w11 = zw1 * yw1;
        int   o00 = zo0 + yo0, o01 = zo0 + yo1, o10 = zo1 + yo0, o11 = zo1 + yo1;

        float r = 0.0f, g = 0.0f, bl = 0.0f;
#define CORNER(W, O) { \
        const int off0 = (O) + xc0, off1 = (O) + xc1; \
        const float wg0 = (W) * xw0, wg1 = (W) * xw1; \
        r  = fmaf(imb[off0],          wg0, r);  r  = fmaf(imb[off1],          wg1, r);  \
        g  = fmaf(imb[262144 + off0], wg0, g);  g  = fmaf(imb[262144 + off1], wg1, g);  \
        bl = fmaf(imb[524288 + off0], wg0, bl); bl = fmaf(imb[524288 + off1], wg1, bl); }
        CORNER(w00, o00) CORNER(w01, o01) CORNER(w10, o10) CORNER(w11, o11)
#undef CORNER
        vr[i] = r; vg[i] = g; vb[i] = bl;
    }

    const float C0 = P.C[b][0], C1 = P.C[b][1], C2  = P.C[b][2],  C3  = P.C[b][3];
    const float C4 = P.C[b][4], C5 = P.C[b][5], C6  = P.C[b][6],  C7  = P.C[b][7];
    const float C8 = P.C[b][8], C9 = P.C[b][9], C10 = P.C[b][10], C11 = P.C[b][11];
    const float sg = P.sigma[b];
    const uint32_t nk0 = P.nk0, nk1 = P.nk1;
    const uint32_t lbase = (uint32_t)b * 786432u +
                           ((uint32_t)z << 12) + ((uint32_t)y << 6) + (uint32_t)x4;

    // cutout: y/z decided once per thread
    const bool keepyz = (fabsf(((float)y + 0.5f) * 0.015625f - P.cy[b]) >= 0.25f) ||
                        (fabsf(((float)z + 0.5f) * 0.015625f - P.cz[b]) >= 0.25f);
    const float ccx = P.cx[b];

    float q0[4], q1[4], q2[4];
#pragma unroll
    for (int i = 0; i < 4; ++i) {
        float r = vr[i], g = vg[i], bl = vb[i];
        float o0 = fmaf(C0, r, fmaf(C1, g, fmaf(C2,  bl, C3)));
        float o1 = fmaf(C4, r, fmaf(C5, g, fmaf(C6,  bl, C7)));
        float o2 = fmaf(C8, r, fmaf(C9, g, fmaf(C10, bl, C11)));

        const uint32_t l = lbase + (uint32_t)i;
        o0 = fmaf(normal_fast(pbits(nk0, nk1, l)),            sg, o0);
        o1 = fmaf(normal_fast(pbits(nk0, nk1, l + 262144u)),  sg, o1);
        o2 = fmaf(normal_fast(pbits(nk0, nk1, l + 524288u)),  sg, o2);

        float fxn = ((float)(x4 + i) + 0.5f) * 0.015625f;
        bool keep = keepyz || (fabsf(fxn - ccx) >= 0.25f);
        float mk = keep ? 1.0f : 0.0f;
        q0[i] = o0 * mk; q1[i] = o1 * mk; q2[i] = o2 * mk;
    }

    float* outb = out + (size_t)b * 786432 +
                  (((size_t)z << 12) + ((size_t)y << 6) + (size_t)x4);
    *reinterpret_cast<float4*>(outb)          = make_float4(q0[0], q0[1], q0[2], q0[3]);
    *reinterpret_cast<float4*>(outb + 262144) = make_float4(q1[0], q1[1], q1[2], q1[3]);
    *reinterpret_cast<float4*>(outb + 524288) = make_float4(q2[0], q2[1], q2[2], q2[3]);
}

// ---------------------------------------------------------------------------
extern "C" void kernel_launch(void* const* d_in, const int* in_sizes, int n_in,
                              void* d_out, int out_size, void* d_ws, size_t ws_size,
                              hipStream_t stream) {
    const float* in = (const float*)d_in[0];
    float* out = (float*)d_out;

    AugParams P;
    build_params(P);  // pure host math, deterministic, graph-capture safe

    dim3 grid(4096), block(256);
    aug_kernel<<<grid, block, 0, stream>>>(in, out, P);
}

// Round 4
// 94.681 us; speedup vs baseline: 2.1754x; 2.1754x over previous
//
#include <hip/hip_runtime.h>
#include <cstring>
#include <cstdint>
#include <cmath>

// ---------------------------------------------------------------------------
// Threefry-2x32 (20 rounds) — exact JAX PRNG
// ---------------------------------------------------------------------------
__host__ __device__ static inline uint32_t rotl32(uint32_t v, int r) {
    return __builtin_rotateleft32(v, (unsigned)r);
}

__host__ __device__ static inline void tf2x32(uint32_t k0, uint32_t k1,
                                              uint32_t& x0, uint32_t& x1) {
    uint32_t ks2 = k0 ^ k1 ^ 0x1BD11BDAu;
    x0 += k0; x1 += k1;
#define TFR(r) { x0 += x1; x1 = rotl32(x1, r); x1 ^= x0; }
    TFR(13) TFR(15) TFR(26) TFR(6)
    x0 += k1;  x1 += ks2 + 1u;
    TFR(17) TFR(29) TFR(16) TFR(24)
    x0 += ks2; x1 += k0 + 2u;
    TFR(13) TFR(15) TFR(26) TFR(6)
    x0 += k0;  x1 += k1 + 3u;
    TFR(17) TFR(29) TFR(16) TFR(24)
    x0 += k1;  x1 += ks2 + 4u;
    TFR(13) TFR(15) TFR(26) TFR(6)
    x0 += ks2; x1 += k0 + 5u;
#undef TFR
}

// Partitionable-mode 32-bit random bits for flat index i: counter (0,i); out0^out1
__host__ __device__ static inline uint32_t pbits(uint32_t k0, uint32_t k1, uint32_t i) {
    uint32_t a = 0u, b = i;
    tf2x32(k0, k1, a, b);
    return a ^ b;
}

// bits -> uniform [0,1) exactly as jax
__host__ __device__ static inline float bits_to_u01(uint32_t bits) {
    uint32_t u = (bits >> 9) | 0x3f800000u;
    float f; memcpy(&f, &u, 4);
    return f - 1.0f;
}

// XLA ErfInv (Giles 2010, float32) — PRECISE version (host-side params only)
__host__ static inline float erfinv_f(float x) {
    float w = -log1pf(-x * x);
    float p;
    if (w < 5.0f) {
        w = w - 2.5f;
        p = 2.81022636e-08f;
        p = fmaf(p, w, 3.43273939e-07f);
        p = fmaf(p, w, -3.5233877e-06f);
        p = fmaf(p, w, -4.39150654e-06f);
        p = fmaf(p, w, 0.00021858087f);
        p = fmaf(p, w, -0.00125372503f);
        p = fmaf(p, w, -0.00417768164f);
        p = fmaf(p, w, 0.246640727f);
        p = fmaf(p, w, 1.50140941f);
    } else {
        w = sqrtf(w) - 3.0f;
        p = -0.000200214257f;
        p = fmaf(p, w, 0.000100950558f);
        p = fmaf(p, w, 0.00134934322f);
        p = fmaf(p, w, -0.00367342844f);
        p = fmaf(p, w, 0.00573950773f);
        p = fmaf(p, w, -0.0076224613f);
        p = fmaf(p, w, 0.00943887047f);
        p = fmaf(p, w, 1.00167406f);
        p = fmaf(p, w, 2.83297682f);
    }
    return p * x;
}

__host__ static inline float normal_from_bits(uint32_t bits) {
    const float LO = -0.999999940395355224609375f;  // -1 + 2^-24
    float u01 = bits_to_u01(bits);
    float u = u01 * 2.0f + LO;
    u = (u > LO) ? u : LO;
    return 1.4142135623730951f * erfinv_f(u);
}

// ---------------------------------------------------------------------------
// Device-fast normal (validated round 3: output identical to precise path
// within absmax budget): log1p(-x^2) via single-rounded fma + v_log_f32.
// ---------------------------------------------------------------------------
__device__ __forceinline__ float normal_fast(uint32_t bits) {
    const float LO = -0.999999940395355224609375f;
    uint32_t u = (bits >> 9) | 0x3f800000u;
    float x = fmaf(__uint_as_float(u) - 1.0f, 2.0f, LO);
    x = fmaxf(x, LO);
    float t = fmaf(x, -x, 1.0f);            // 1 - x^2, single rounding
    float lg = __log2f(t);                   // v_log_f32
    float p;
    if (__builtin_expect(lg > -7.2134752044448170f, 1)) {   // w < 5
        float w = fmaf(lg, -0.6931471805599453f, -2.5f);
        p = 2.81022636e-08f;
        p = fmaf(p, w, 3.43273939e-07f);
        p = fmaf(p, w, -3.5233877e-06f);
        p = fmaf(p, w, -4.39150654e-06f);
        p = fmaf(p, w, 0.00021858087f);
        p = fmaf(p, w, -0.00125372503f);
        p = fmaf(p, w, -0.00417768164f);
        p = fmaf(p, w, 0.246640727f);
        p = fmaf(p, w, 1.50140941f);
    } else {
        float w = sqrtf(lg * -0.6931471805599453f) - 3.0f;
        p = -0.000200214257f;
        p = fmaf(p, w, 0.000100950558f);
        p = fmaf(p, w, 0.00134934322f);
        p = fmaf(p, w, -0.00367342844f);
        p = fmaf(p, w, 0.00573950773f);
        p = fmaf(p, w, -0.0076224613f);
        p = fmaf(p, w, 0.00943887047f);
        p = fmaf(p, w, 1.00167406f);
        p = fmaf(p, w, 2.83297682f);
    }
    return 1.4142135623730951f * p * x;
}

// Three interleaved threefry chains (same key, counters l, l+256K, l+512K).
// Exposes ILP-3 on the serial add/rotl/xor chains; key-injection sums are SALU.
__device__ __forceinline__ void noise3(uint32_t k0, uint32_t k1, uint32_t l,
                                       float& n0, float& n1, float& n2) {
    const uint32_t ks2 = k0 ^ k1 ^ 0x1BD11BDAu;
    uint32_t a0 = k0, b0 = l + k1;
    uint32_t a1 = k0, b1 = (l + 262144u) + k1;
    uint32_t a2 = k0, b2 = (l + 524288u) + k1;
#define R3(r)      { a0 += b0; b0 = rotl32(b0, r); b0 ^= a0; \
                     a1 += b1; b1 = rotl32(b1, r); b1 ^= a1; \
                     a2 += b2; b2 = rotl32(b2, r); b2 ^= a2; }
#define INJ(ka,kb) { a0 += (ka); b0 += (kb); a1 += (ka); b1 += (kb); a2 += (ka); b2 += (kb); }
    R3(13) R3(15) R3(26) R3(6)  INJ(k1,  ks2 + 1u)
    R3(17) R3(29) R3(16) R3(24) INJ(ks2, k0  + 2u)
    R3(13) R3(15) R3(26) R3(6)  INJ(k0,  k1  + 3u)
    R3(17) R3(29) R3(16) R3(24) INJ(k1,  ks2 + 4u)
    R3(13) R3(15) R3(26) R3(6)  INJ(ks2, k0  + 5u)
#undef R3
#undef INJ
    n0 = normal_fast(a0 ^ b0);
    n1 = normal_fast(a1 ^ b1);
    n2 = normal_fast(a2 ^ b2);
}

// ---------------------------------------------------------------------------
// Host-side float32 4x4 matrix helpers (exact reference mirror)
// ---------------------------------------------------------------------------
struct M4 { float m[4][4]; };

static M4 m4_eye() {
    M4 r;
    for (int i = 0; i < 4; ++i)
        for (int j = 0; j < 4; ++j) r.m[i][j] = (i == j) ? 1.0f : 0.0f;
    return r;
}
static M4 m4_mul(const M4& A, const M4& B) {
    M4 r;
    for (int i = 0; i < 4; ++i)
        for (int j = 0; j < 4; ++j) {
            float s = 0.0f;
            for (int k = 0; k < 4; ++k) s += A.m[i][k] * B.m[k][j];
            r.m[i][j] = s;
        }
    return r;
}
static M4 m4_scale(float sx, float sy, float sz) {
    M4 r = m4_eye(); r.m[0][0] = sx; r.m[1][1] = sy; r.m[2][2] = sz; return r;
}
static M4 m4_trans(float tx, float ty, float tz) {
    M4 r = m4_eye(); r.m[0][3] = tx; r.m[1][3] = ty; r.m[2][3] = tz; return r;
}
static M4 m4_rotz(float th) {
    float c = cosf(th), s = sinf(th);
    M4 r = m4_eye();
    r.m[0][0] = c; r.m[0][1] = -s; r.m[1][0] = s; r.m[1][1] = c;
    return r;
}
static M4 m4_rotluma(float th) {
    const float a  = 0.57735026918962576f;
    const float a2 = 1.0f / 3.0f;
    float c = cosf(th), s = sinf(th), cc = 1.0f - c;
    float d  = a2 * cc + c;
    float mm = a2 * cc - a * s;
    float pp = a2 * cc + a * s;
    M4 r = m4_eye();
    r.m[0][0] = d;  r.m[0][1] = mm; r.m[0][2] = pp;
    r.m[1][0] = pp; r.m[1][1] = d;  r.m[1][2] = mm;
    r.m[2][0] = mm; r.m[2][1] = pp; r.m[2][2] = d;
    return r;
}

// ---------------------------------------------------------------------------
struct AugParams {
    float G[16][12];
    float C[16][12];
    float sigma[16];
    float cx[16], cy[16], cz[16];
    uint32_t nk0, nk1;
};

static void build_params(AugParams& P) {
    uint32_t sk0[24], sk1[24];
    for (int j = 0; j < 24; ++j) {
        uint32_t a = 0u, b = (uint32_t)j;
        tf2x32(0u, 42u, a, b);
        sk0[j] = a; sk1[j] = b;
    }

    float u_xf[16], u_r90[16], u_ti[48], n_sc[16], u_r1[16], n_an[16], u_r2[16];
    float n_tf[48], n_br[16], n_ct[16], u_lf[16], u_hue[16], n_sat[16], n_sig[16], u_cut[48];

    auto fill_u = [&](int j, int n, float* o) {
        for (int i = 0; i < n; ++i) o[i] = bits_to_u01(pbits(sk0[j], sk1[j], (uint32_t)i));
    };
    auto fill_n = [&](int j, int n, float* o) {
        for (int i = 0; i < n; ++i) o[i] = normal_from_bits(pbits(sk0[j], sk1[j], (uint32_t)i));
    };

    fill_u(0, 16, u_xf);  fill_u(1, 16, u_r90);  fill_u(2, 48, u_ti);
    fill_n(3, 16, n_sc);  fill_u(4, 16, u_r1);   fill_n(5, 16, n_an);
    fill_u(6, 16, u_r2);  fill_n(7, 48, n_tf);   fill_n(8, 16, n_br);
    fill_n(9, 16, n_ct);  fill_u(10, 16, u_lf);  fill_u(11, 16, u_hue);
    fill_n(12, 16, n_sat); fill_n(13, 16, n_sig); fill_u(15, 48, u_cut);
    P.nk0 = sk0[14]; P.nk1 = sk1[14];

    const float PI_F = 3.14159265358979323846f;
    const float HPI_F = 1.5707963267948966f;

    for (int b = 0; b < 16; ++b) {
        M4 G = m4_eye();
        float i1 = floorf(u_xf[b] * 2.0f);
        G = m4_mul(G, m4_scale(1.0f - 2.0f * i1, 1.0f, 1.0f));
        float i2 = floorf(u_r90[b] * 4.0f);
        G = m4_mul(G, m4_rotz(-HPI_F * i2));
        float t0 = (u_ti[3 * b + 0] * 2.0f - 1.0f) * 0.125f;
        float t1 = (u_ti[3 * b + 1] * 2.0f - 1.0f) * 0.125f;
        float t2 = (u_ti[3 * b + 2] * 2.0f - 1.0f) * 0.125f;
        G = m4_mul(G, m4_trans(-rintf(t0 * 64.0f), -rintf(t1 * 64.0f), -rintf(t2 * 64.0f)));
        float s = exp2f(n_sc[b] * 0.2f);
        G = m4_mul(G, m4_scale(1.0f / s, 1.0f / s, 1.0f / s));
        float th1 = (u_r1[b] * 2.0f - 1.0f) * PI_F;
        G = m4_mul(G, m4_rotz(-th1));
        float s2 = exp2f(n_an[b] * 0.2f);
        G = m4_mul(G, m4_scale(1.0f / s2, s2, 1.0f));
        float th2 = (u_r2[b] * 2.0f - 1.0f) * PI_F;
        G = m4_mul(G, m4_rotz(-th2));
        float f0 = n_tf[3 * b + 0] * 0.125f;
        float f1 = n_tf[3 * b + 1] * 0.125f;
        float f2 = n_tf[3 * b + 2] * 0.125f;
        G = m4_mul(G, m4_trans(-f0 * 64.0f, -f1 * 64.0f, -f2 * 64.0f));

        M4 C = m4_eye();
        float br = n_br[b] * 0.2f;
        C = m4_mul(m4_trans(br, br, br), C);
        float ct = exp2f(n_ct[b] * 0.5f);
        C = m4_mul(m4_scale(ct, ct, ct), C);
        const float va = 0.57735026918962576f;
        float v4[4] = { va, va, va, 0.0f };
        float ilf = floorf(u_lf[b] * 2.0f);
        M4 L;
        for (int r = 0; r < 4; ++r)
            for (int c = 0; c < 4; ++c)
                L.m[r][c] = ((r == c) ? 1.0f : 0.0f) - 2.0f * (v4[r] * v4[c]) * ilf;
        C = m4_mul(L, C);
        float thh = (u_hue[b] * 2.0f - 1.0f) * PI_F;
        C = m4_mul(m4_rotluma(thh), C);
        float ss = exp2f(n_sat[b] * 1.0f);
        M4 S;
        for (int r = 0; r < 4; ++r)
            for (int c = 0; c < 4; ++c) {
                float vv = v4[r] * v4[c];
                S.m[r][c] = vv + (((r == c) ? 1.0f : 0.0f) - vv) * ss;
            }
        C = m4_mul(S, C);

        P.sigma[b] = fabsf(n_sig[b]) * 0.1f;
        P.cx[b] = u_cut[3 * b + 0];
        P.cy[b] = u_cut[3 * b + 1];
        P.cz[b] = u_cut[3 * b + 2];
        for (int r = 0; r < 3; ++r)
            for (int c = 0; c < 4; ++c) {
                P.G[b][r * 4 + c] = G.m[r][c];
                P.C[b][r * 4 + c] = C.m[r][c];
            }
    }
}

// ---------------------------------------------------------------------------
// Fused augment kernel: 1 voxel/thread (lane-consecutive x — proven coalesced),
// folded-validity gather, interleaved triple-threefry noise.
// ---------------------------------------------------------------------------
__global__ __launch_bounds__(256, 4) void aug_kernel(const float* __restrict__ in,
                                                     float* __restrict__ out,
                                                     AugParams P) {
    const int bid = blockIdx.x;
    const int b = bid >> 10;                              // 1024 blocks per batch
    const int vox = ((bid & 1023) << 8) | threadIdx.x;    // 0..262143
    const int x = vox & 63;
    const int y = (vox >> 6) & 63;
    const int z = vox >> 12;

    const float* Gb = P.G[b];
    const float hx = (float)x - 31.5f;
    const float hy = (float)y - 31.5f;
    const float hz = (float)z - 31.5f;
    float sx = Gb[0] * hx + Gb[1] * hy + Gb[2]  * hz + Gb[3]  + 31.5f;
    float sy = Gb[4] * hx + Gb[5] * hy + Gb[6]  * hz + Gb[7]  + 31.5f;
    float sz = Gb[8] * hx + Gb[9] * hy + Gb[10] * hz + Gb[11] + 31.5f;

    float fx = floorf(sx), fy = floorf(sy), fz = floorf(sz);
    float wx = sx - fx, wy = sy - fy, wz = sz - fz;
    int ix = (int)fx, iy = (int)fy, iz = (int)fz;

    // validity folded into axis weights (invalid -> 0 weight)
    float xw0 = ((unsigned)ix       < 64u) ? 1.0f - wx : 0.0f;
    float xw1 = ((unsigned)(ix + 1) < 64u) ? wx        : 0.0f;
    float yw0 = ((unsigned)iy       < 64u) ? 1.0f - wy : 0.0f;
    float yw1 = ((unsigned)(iy + 1) < 64u) ? wy        : 0.0f;
    float zw0 = ((unsigned)iz       < 64u) ? 1.0f - wz : 0.0f;
    float zw1 = ((unsigned)(iz + 1) < 64u) ? wz        : 0.0f;

    // clamped offsets (memory safety; weight 0 kills any garbage, input finite)
    int xc0 = min(max(ix, 0), 63),       xc1 = min(max(ix + 1, 0), 63);
    int yo0 = min(max(iy, 0), 63) << 6,  yo1 = min(max(iy + 1, 0), 63) << 6;
    int zo0 = min(max(iz, 0), 63) << 12, zo1 = min(max(iz + 1, 0), 63) << 12;

    float w00 = zw0 * yw0, w01 = zw0 * yw1, w10 = zw1 * yw0, w11 = zw1 * yw1;
    int   o00 = zo0 + yo0, o01 = zo0 + yo1, o10 = zo1 + yo0, o11 = zo1 + yo1;

    const float* __restrict__ imb = in + (size_t)b * 786432;
    float r = 0.0f, g = 0.0f, bl = 0.0f;
#define CORNER(W, O) { \
    const int off0 = (O) + xc0, off1 = (O) + xc1; \
    const float wg0 = (W) * xw0, wg1 = (W) * xw1; \
    r  = fmaf(imb[off0],          wg0, r);  r  = fmaf(imb[off1],          wg1, r);  \
    g  = fmaf(imb[262144 + off0], wg0, g);  g  = fmaf(imb[262144 + off1], wg1, g);  \
    bl = fmaf(imb[524288 + off0], wg0, bl); bl = fmaf(imb[524288 + off1], wg1, bl); }
    CORNER(w00, o00) CORNER(w01, o01) CORNER(w10, o10) CORNER(w11, o11)
#undef CORNER

    // noise: 3 interleaved threefry chains
    const uint32_t l0 = (uint32_t)b * 786432u + (uint32_t)vox;
    float n0, n1, n2;
    noise3(P.nk0, P.nk1, l0, n0, n1, n2);

    // color transform + noise
    const float* Cb = P.C[b];
    const float sg = P.sigma[b];
    float o0 = fmaf(Cb[0], r, fmaf(Cb[1], g, fmaf(Cb[2],  bl, Cb[3])));
    float o1 = fmaf(Cb[4], r, fmaf(Cb[5], g, fmaf(Cb[6],  bl, Cb[7])));
    float o2 = fmaf(Cb[8], r, fmaf(Cb[9], g, fmaf(Cb[10], bl, Cb[11])));
    o0 = fmaf(n0, sg, o0);
    o1 = fmaf(n1, sg, o1);
    o2 = fmaf(n2, sg, o2);

    // cutout (bit-exact: all operands exact f32)
    float fxn = ((float)x + 0.5f) * 0.015625f;
    float fyn = ((float)y + 0.5f) * 0.015625f;
    float fzn = ((float)z + 0.5f) * 0.015625f;
    bool keep = (fabsf(fxn - P.cx[b]) >= 0.25f) ||
                (fabsf(fyn - P.cy[b]) >= 0.25f) ||
                (fabsf(fzn - P.cz[b]) >= 0.25f);
    float mk = keep ? 1.0f : 0.0f;

    size_t ob = (size_t)b * 786432 + (size_t)vox;
    out[ob]           = o0 * mk;
    out[ob + 262144]  = o1 * mk;
    out[ob + 524288]  = o2 * mk;
}

// ---------------------------------------------------------------------------
extern "C" void kernel_launch(void* const* d_in, const int* in_sizes, int n_in,
                              void* d_out, int out_size, void* d_ws, size_t ws_size,
                              hipStream_t stream) {
    const float* in = (const float*)d_in[0];
    float* out = (float*)d_out;

    AugParams P;
    build_params(P);  // pure host math, deterministic, graph-capture safe

    dim3 grid(16 * 1024), block(256);
    aug_kernel<<<grid, block, 0, stream>>>(in, out, P);
}